// Round 9
// baseline (3040.610 us; speedup 1.0000x reference)
//
#include <hip/hip_runtime.h>
#include <hip/hip_bf16.h>
#include <math.h>

#define BB   128
#define TT   2048
#define DD   4
#define HH   64
#define WIN  10
#define TILE 64
#define RWS  (TILE + WIN)   // 74 rows per attention tile (halo included)

// ---------- fast activations ----------
__device__ __forceinline__ float sigf(float x) {
    return __fdividef(1.f, 1.f + __expf(-x));
}
__device__ __forceinline__ float dot4(float4 a, float4 b) {
    return a.x*b.x + a.y*b.y + a.z*b.z + a.w*b.w;
}

// DPP helpers (VALU-speed cross-lane)
#define QB(x, imm) __int_as_float(__builtin_amdgcn_mov_dpp(__float_as_int(x), (imm), 0xF, 0xF, true))
__device__ __forceinline__ float red16(float x) {  // sum over 16-lane group, pure DPP
    x = x + QB(x, 0xB1);    // quad_perm xor1
    x = x + QB(x, 0x4E);    // quad_perm xor2
    x = x + QB(x, 0x141);   // row_half_mirror: 4-groups swap within each 8
    x = x + QB(x, 0x140);   // row_mirror: 8-halves swap within each 16
    return x;
}

// Quad-split LSTM activation: lane q=tid&3 computes gate q's activation
// (tanh via 2*sig(2z)-1, uniform code, no divergence), quad-broadcasts,
// updates c and h identically in all lanes.
__device__ __forceinline__ void act_update(const float gv0, const float gv1,
                                           const float gv2, const float gv3,
                                           const int q, float& c, float& h) {
    float y = gv0;
    y = (q == 1) ? gv1 : y;
    y = (q == 2) ? gv2 : y;
    y = (q == 3) ? gv3 : y;
    y = (q == 2) ? y + y : y;            // tanh gate: pre-scale 2x
    float s = sigf(y);
    s = (q == 2) ? s + s - 1.f : s;      // tanh(z) = 2*sig(2z)-1
    const float ii = QB(s, 0x00);
    const float ff = QB(s, 0x55);
    const float gg = QB(s, 0xAA);
    const float oo = QB(s, 0xFF);
    c = ff * c + ii * gg;
    h = oo * (2.f * sigf(c + c) - 1.f);  // oo * tanh(c)
}

#define PIN4(v) asm volatile("" : "+v"(v.x), "+v"(v.y), "+v"(v.z), "+v"(v.w))

// =====================================================================
// Kernel 1: 2-layer LSTM. One WG (1024 threads = 16 waves) per batch.
// thread = (unit u = tid>>4, k-slice s = tid&15, 4-wide slices).
// R8 post-mortem: at 512 thr the 96 weight floats/thread exceeded the
// allocator's LDS-derived budget (~85 VGPR at its 6-waves/EU target) and
// were parked in AGPRs; only 2 waves/SIMD hid the ~120cyc ds_read +
// barrier + activation chain. Now: 48 weights/thread (+~40 working < 128
// budget) with occupancy pinned to exactly 4 waves/EU -> weights stay in
// arch VGPRs AND 2x the waves to hide the serial-chain latency.
// red16 = 4 pure-DPP stages. Activations quad-split. h1 output buffered
// in LDS, flushed every 64 steps.
// =====================================================================
__global__ __launch_bounds__(1024, 1) __attribute__((amdgpu_waves_per_eu(4, 4)))
void lstm_kernel(const float* __restrict__ x,
                 const float* __restrict__ Wih0, const float* __restrict__ Whh0,
                 const float* __restrict__ bih0, const float* __restrict__ bhh0,
                 const float* __restrict__ Wih1, const float* __restrict__ Whh1,
                 const float* __restrict__ bih1, const float* __restrict__ bhh1,
                 float* __restrict__ lstm_out) {
    __shared__ __align__(16) float h0s[2][HH];
    __shared__ __align__(16) float h1s[2][HH];
    __shared__ __align__(16) float xall[TT * DD];    // 32 KB
    __shared__ __align__(16) float hbuf[64 * HH];    // 16 KB output chunk

    const int tid = threadIdx.x;
    const int u   = tid >> 4;     // hidden unit 0..63
    const int s   = tid & 15;     // k-slice 0..15 (k = 4s..4s+3)
    const int q   = tid & 3;      // quad lane (gate index for activation)
    const int b   = blockIdx.x;

    // ---- weights into registers (12 float4 = 48 VGPR target) ----
    float4 wh0[4], wi1[4], wh1[4];
    float  wx[4], b0g[4], b1g[4];
#pragma unroll
    for (int g = 0; g < 4; ++g) {
        const int row = g * 64 + u;
        wh0[g] = *(const float4*)(Whh0 + row * 64 + 4 * s);
        wi1[g] = *(const float4*)(Wih1 + row * 64 + 4 * s);
        wh1[g] = *(const float4*)(Whh1 + row * 64 + 4 * s);
        wx[g]  = (s < 4) ? Wih0[row * 4 + s] : 0.f;   // x-term carried by lanes s<4
        b0g[g] = bih0[row] + bhh0[row];
        b1g[g] = bih1[row] + bhh1[row];
    }
    // pin: opaque values -> no rematerialization of the loads
#pragma unroll
    for (int g = 0; g < 4; ++g) {
        PIN4(wh0[g]);
        PIN4(wi1[g]);
        PIN4(wh1[g]);
        asm volatile("" : "+v"(wx[g]), "+v"(b0g[g]), "+v"(b1g[g]));
    }

    // ---- stage all x for this batch ----
    const float* xrow = x + (size_t)b * TT * DD;
    for (int i = tid; i < TT; i += 1024)
        *(float4*)(xall + i * 4) = *(const float4*)(xrow + i * 4);
    if (tid < HH) h1s[1][tid] = 0.f;
    float c0 = 0.f, c1 = 0.f;
    __syncthreads();

    // ---- t=0 layer 0 (h0_prev = 0) ----
    {
        const float xa = xall[s & 3];
        float g0v[4];
#pragma unroll
        for (int g = 0; g < 4; ++g) g0v[g] = red16(wx[g] * xa) + b0g[g];
        float h0v;
        act_update(g0v[0], g0v[1], g0v[2], g0v[3], q, c0, h0v);
        if (s == 0) h0s[0][u] = h0v;
    }

    float* orow = lstm_out + (size_t)b * TT * HH;

    for (int t = 0; t < TT; ++t) {
        __syncthreads();                        // one barrier per step
        const float4 h0v4 = *(const float4*)(h0s[t & 1] + 4 * s);        // h0(t)
        const float4 h1v4 = *(const float4*)(h1s[(t + 1) & 1] + 4 * s);  // h1(t-1)

        // layer-1 gate partials
        float g1v[4], g0v[4];
#pragma unroll
        for (int g = 0; g < 4; ++g)
            g1v[g] = dot4(wi1[g], h0v4) + dot4(wh1[g], h1v4);
        // layer-0(t+1) partials
        const float xa = xall[(t + 1 < TT ? t + 1 : t) * 4 + (s & 3)];
#pragma unroll
        for (int g = 0; g < 4; ++g)
            g0v[g] = wx[g] * xa + dot4(wh0[g], h0v4);
#pragma unroll
        for (int g = 0; g < 4; ++g) g1v[g] = red16(g1v[g]) + b1g[g];
#pragma unroll
        for (int g = 0; g < 4; ++g) g0v[g] = red16(g0v[g]) + b0g[g];

        {   // layer-1 activations
            float h1vv;
            act_update(g1v[0], g1v[1], g1v[2], g1v[3], q, c1, h1vv);
            if (s == 0) h1s[t & 1][u] = h1vv;
            if (s == 1) hbuf[(t & 63) * HH + u] = h1vv;
        }
        if (t + 1 < TT) {   // layer-0 activations for t+1
            float h0vv;
            act_update(g0v[0], g0v[1], g0v[2], g0v[3], q, c0, h0vv);
            if (s == 0) h0s[(t + 1) & 1][u] = h0vv;
        }
        if ((t & 63) == 63) {                   // chunk flush (1 vmcnt drain / 64 steps)
            __syncthreads();
            ((float4*)(orow + (size_t)(t - 63) * HH))[tid] = ((const float4*)hbuf)[tid];
        }
    }
}

// =====================================================================
// Kernel 2: fused q/k/v + windowed attention + MLP head. (unchanged R3)
// Weights read directly from global (L1/L2 broadcast across WGs); LDS
// holds only data tiles (78 KB) -> 2 WGs/CU.
// =====================================================================
#define ATTN_LDS_FLOATS 19560

__global__ __launch_bounds__(256, 2)
void attn_kernel(const float* __restrict__ lstm,
                 const float* __restrict__ Wq, const float* __restrict__ bq,
                 const float* __restrict__ Wk, const float* __restrict__ bk,
                 const float* __restrict__ Wv, const float* __restrict__ bv,
                 const float* __restrict__ Wc, const float* __restrict__ bc,
                 const float* __restrict__ Wo1, const float* __restrict__ bo1,
                 const float* __restrict__ Wo2, const float* __restrict__ bo2,
                 float* __restrict__ out) {
    extern __shared__ __align__(16) float lds[];
    float* bias = lds;            // [256]
    float* ho   = lds + 256;      // [74][64]
    float* kb   = lds + 4992;     // [74][36]
    float* qb   = lds + 7656;     // [64][36]
    float* vb   = lds + 9960;     // [74][64]
    float* swr  = lds + 14696;    // [64][12]
    float* ctxs = lds + 15464;    // [64][64]
    float* cmbs = lds + 4992;     // [64][64] alias (kb+qb dead after scores)
    float* o1s  = lds + 9960;     // [64][33] alias (vb dead after context)

    const int tid  = threadIdx.x;
    const int b    = blockIdx.x >> 5;
    const int tile = blockIdx.x & 31;
    const int t0   = tile * TILE;

    if (tid < 32) {
        bias[tid]       = bq[tid];
        bias[32 + tid]  = bk[tid];
        bias[192 + tid] = bo1[tid];
        bias[224 + tid] = Wo2[tid];
    }
    if (tid >= 64 && tid < 128) {
        const int j = tid - 64;
        bias[64 + j]  = bv[j];
        bias[128 + j] = bc[j];
    }
    for (int i = tid; i < RWS * 16; i += 256) {
        const int row = i >> 4, c = i & 15;
        const int t = t0 - WIN + row;
        float4 v = make_float4(0.f, 0.f, 0.f, 0.f);
        if (t >= 0) v = *(const float4*)(lstm + ((size_t)b * TT + t) * HH + 4 * c);
        *(float4*)(ho + row * 64 + 4 * c) = v;
    }
    __syncthreads();

    // ---- phase 1a: v projection ----
    {
        const int h = tid & 63, rq = tid >> 6;
        const int r0 = rq * 19;
        int ri[19];
        float acc[19];
#pragma unroll
        for (int rr = 0; rr < 19; ++rr) { ri[rr] = min(r0 + rr, RWS - 1); acc[rr] = bias[64 + h]; }
#pragma unroll
        for (int k4 = 0; k4 < 16; ++k4) {
            const float4 w = *(const float4*)(Wv + h * 64 + 4 * k4);
#pragma unroll
            for (int rr = 0; rr < 19; ++rr)
                acc[rr] += dot4(w, *(const float4*)(ho + ri[rr] * 64 + 4 * k4));
        }
#pragma unroll
        for (int rr = 0; rr < 19; ++rr) vb[ri[rr] * 64 + h] = acc[rr];
    }
    // ---- phase 1b: k projection ----
    {
        const int a = tid & 31, rq = tid >> 5;
        const int r0 = rq * 10;
        int ri[10];
        float acc[10];
#pragma unroll
        for (int rr = 0; rr < 10; ++rr) { ri[rr] = min(r0 + rr, RWS - 1); acc[rr] = bias[32 + a]; }
#pragma unroll
        for (int k4 = 0; k4 < 16; ++k4) {
            const float4 w = *(const float4*)(Wk + a * 64 + 4 * k4);
#pragma unroll
            for (int rr = 0; rr < 10; ++rr)
                acc[rr] += dot4(w, *(const float4*)(ho + ri[rr] * 64 + 4 * k4));
        }
#pragma unroll
        for (int rr = 0; rr < 10; ++rr) kb[ri[rr] * 36 + a] = acc[rr];
    }
    // ---- phase 1c: q projection ----
    {
        const int a = tid & 31, rq = tid >> 5;
        float acc[8];
#pragma unroll
        for (int rr = 0; rr < 8; ++rr) acc[rr] = bias[a];
#pragma unroll
        for (int k4 = 0; k4 < 16; ++k4) {
            const float4 w = *(const float4*)(Wq + a * 64 + 4 * k4);
#pragma unroll
            for (int rr = 0; rr < 8; ++rr)
                acc[rr] += dot4(w, *(const float4*)(ho + (rq * 8 + rr + WIN) * 64 + 4 * k4));
        }
#pragma unroll
        for (int rr = 0; rr < 8; ++rr) qb[(rq * 8 + rr) * 36 + a] = acc[rr];
    }
    __syncthreads();

    // ---- phase 2a: scores ----
    for (int i = tid; i < TILE * WIN; i += 256) {
        const int r = i / WIN, l = i - r * WIN;
        const int t = t0 + r;
        float s = -1e30f;
        if (t - 1 - l >= 0) {
            const int kr = r + WIN - 1 - l;
            float acc = 0.f;
#pragma unroll
            for (int a4 = 0; a4 < 8; ++a4)
                acc += dot4(*(const float4*)(qb + r * 36 + 4 * a4),
                            *(const float4*)(kb + kr * 36 + 4 * a4));
            s = acc * 0.17677669529663687f;   // 1/sqrt(32)
        }
        swr[r * 12 + l] = s;
    }
    __syncthreads();
    // ---- phase 2b: softmax per row ----
    if (tid < TILE) {
        const int r = tid;
        float sc[WIN], m = -1e30f;
#pragma unroll
        for (int l = 0; l < WIN; ++l) { sc[l] = swr[r * 12 + l]; m = fmaxf(m, sc[l]); }
        float sum = 0.f;
#pragma unroll
        for (int l = 0; l < WIN; ++l) { sc[l] = __expf(sc[l] - m); sum += sc[l]; }
        const float inv = __fdividef(1.f, sum);
#pragma unroll
        for (int l = 0; l < WIN; ++l) swr[r * 12 + l] = sc[l] * inv;
    }
    __syncthreads();
    // ---- phase 2c: context ----
    for (int i = tid; i < TILE * HH; i += 256) {
        const int r = i >> 6, h = i & 63;
        float acc = 0.f;
#pragma unroll
        for (int l = 0; l < WIN; ++l)
            acc += swr[r * 12 + l] * vb[(r + WIN - 1 - l) * 64 + h];
        ctxs[r * 64 + h] = acc;
    }
    __syncthreads();

    // ---- phase 3: combined ----
    {
        const int h = tid & 63, rq = tid >> 6;
        float acc[16];
#pragma unroll
        for (int rr = 0; rr < 16; ++rr) acc[rr] = bias[128 + h];
#pragma unroll
        for (int k4 = 0; k4 < 16; ++k4) {
            const float4 w = *(const float4*)(Wc + h * 128 + 4 * k4);
#pragma unroll
            for (int rr = 0; rr < 16; ++rr)
                acc[rr] += dot4(w, *(const float4*)(ho + (rq * 16 + rr + WIN) * 64 + 4 * k4));
        }
#pragma unroll
        for (int k4 = 0; k4 < 16; ++k4) {
            const float4 w = *(const float4*)(Wc + h * 128 + 64 + 4 * k4);
#pragma unroll
            for (int rr = 0; rr < 16; ++rr)
                acc[rr] += dot4(w, *(const float4*)(ctxs + (rq * 16 + rr) * 64 + 4 * k4));
        }
        if (t0 == 0 && rq == 0) acc[0] = ho[WIN * 64 + h];   // t==0 bypass
#pragma unroll
        for (int rr = 0; rr < 16; ++rr) cmbs[(rq * 16 + rr) * 64 + h] = acc[rr];
    }
    __syncthreads();

    // ---- phase 4: o1 ----
    {
        const int m = tid & 31, rq = tid >> 5;
        float acc[8];
#pragma unroll
        for (int rr = 0; rr < 8; ++rr) acc[rr] = bias[192 + m];
#pragma unroll
        for (int k4 = 0; k4 < 16; ++k4) {
            const float4 w = *(const float4*)(Wo1 + m * 64 + 4 * k4);
#pragma unroll
            for (int rr = 0; rr < 8; ++rr)
                acc[rr] += dot4(w, *(const float4*)(cmbs + (rq * 8 + rr) * 64 + 4 * k4));
        }
#pragma unroll
        for (int rr = 0; rr < 8; ++rr)
            o1s[(rq * 8 + rr) * 33 + m] = fmaxf(acc[rr], 0.f);
    }
    __syncthreads();

    // ---- phase 5: out ----
    if (tid < TILE) {
        const int r = tid;
        float s = bo2[0];
#pragma unroll
        for (int m = 0; m < 32; ++m) s += o1s[r * 33 + m] * bias[224 + m];
        out[(size_t)b * TT + t0 + r] = 1.5f * tanhf(s);
    }
}

// =====================================================================
extern "C" void kernel_launch(void* const* d_in, const int* in_sizes, int n_in,
                              void* d_out, int out_size, void* d_ws, size_t ws_size,
                              hipStream_t stream) {
    const float* x    = (const float*)d_in[0];
    const float* Wih0 = (const float*)d_in[1];
    const float* Whh0 = (const float*)d_in[2];
    const float* bih0 = (const float*)d_in[3];
    const float* bhh0 = (const float*)d_in[4];
    const float* Wih1 = (const float*)d_in[5];
    const float* Whh1 = (const float*)d_in[6];
    const float* bih1 = (const float*)d_in[7];
    const float* bhh1 = (const float*)d_in[8];
    const float* Wq   = (const float*)d_in[9];
    const float* bq   = (const float*)d_in[10];
    const float* Wk   = (const float*)d_in[11];
    const float* bk   = (const float*)d_in[12];
    const float* Wv   = (const float*)d_in[13];
    const float* bv   = (const float*)d_in[14];
    const float* Wc   = (const float*)d_in[15];
    const float* bc   = (const float*)d_in[16];
    const float* Wo1  = (const float*)d_in[17];
    const float* bo1  = (const float*)d_in[18];
    const float* Wo2  = (const float*)d_in[19];
    const float* bo2  = (const float*)d_in[20];
    float* out = (float*)d_out;

    float* lstm_out = (float*)d_ws;   // B*T*H floats = 64 MB

    lstm_kernel<<<BB, 1024, 0, stream>>>(x, Wih0, Whh0, bih0, bhh0,
                                         Wih1, Whh1, bih1, bhh1, lstm_out);

    const int LDS_BYTES = ATTN_LDS_FLOATS * 4;   // 78240
    hipFuncSetAttribute(reinterpret_cast<const void*>(attn_kernel),
                        hipFuncAttributeMaxDynamicSharedMemorySize, LDS_BYTES);
    attn_kernel<<<BB * (TT / TILE), 256, LDS_BYTES, stream>>>(
        lstm_out, Wq, bq, Wk, bk, Wv, bv, Wc, bc, Wo1, bo1, Wo2, bo2, out);
}

// Round 10
// 1819.851 us; speedup vs baseline: 1.6708x; 1.6708x over previous
//
#include <hip/hip_runtime.h>
#include <hip/hip_bf16.h>
#include <math.h>

#define BB   128
#define TT   2048
#define DD   4
#define HH   64
#define WIN  10
#define TILE 64
#define RWS  (TILE + WIN)   // 74 rows per attention tile (halo included)

// ---------- fast activations ----------
__device__ __forceinline__ float sigf(float x) {
    return __fdividef(1.f, 1.f + __expf(-x));
}
__device__ __forceinline__ float dot4(float4 a, float4 b) {
    return a.x*b.x + a.y*b.y + a.z*b.z + a.w*b.w;
}

// DPP helpers (VALU-speed cross-lane)
#define QB(x, imm) __int_as_float(__builtin_amdgcn_mov_dpp(__float_as_int(x), (imm), 0xF, 0xF, true))
__device__ __forceinline__ float red4(float x) {   // sum over quad, 2 DPP stages
    x = x + QB(x, 0xB1);    // quad_perm xor1
    x = x + QB(x, 0x4E);    // quad_perm xor2
    return x;
}
__device__ __forceinline__ float red8(float x) {   // sum over 8-lane group
    x = x + QB(x, 0xB1);
    x = x + QB(x, 0x4E);
    x = x + QB(x, 0x141);   // row_half_mirror: mirrors within each 8-lane half-row
    return x;
}

// Quad-split LSTM activation: lane q computes gate q's activation
// (tanh via 2*sig(2z)-1, uniform code), quad-broadcasts, updates c,h.
__device__ __forceinline__ void act_update(const float gv0, const float gv1,
                                           const float gv2, const float gv3,
                                           const int q, float& c, float& h) {
    float y = gv0;
    y = (q == 1) ? gv1 : y;
    y = (q == 2) ? gv2 : y;
    y = (q == 3) ? gv3 : y;
    y = (q == 2) ? y + y : y;            // tanh gate: pre-scale 2x
    float s = sigf(y);
    s = (q == 2) ? s + s - 1.f : s;      // tanh(z) = 2*sig(2z)-1
    const float ii = QB(s, 0x00);
    const float ff = QB(s, 0x55);
    const float gg = QB(s, 0xAA);
    const float oo = QB(s, 0xFF);
    c = ff * c + ii * gg;
    h = oo * (2.f * sigf(c + c) - 1.f);  // oo * tanh(c)
}

#define PIN4(v) asm volatile("" : "+v"(v.x), "+v"(v.y), "+v"(v.z), "+v"(v.w))

// =====================================================================
// Kernel 1: 2-layer LSTM, ROLE-SPLIT waves. One WG (768 thr) per batch.
//  Group A (tid<256,  waves 0-3):  layer 0. thread=(u=tid>>2, p=tid&3),
//    16-wide k-slices of h0 + x[d=p]. red4 (2 DPP stages).
//  Group B (tid>=256, waves 4-11): layer 1. thread=(u=btid>>3, p=btid&7),
//    p<4 reads h0[16p..), p>=4 reads h1[16(p-4)..). red8.
// Rationale (R8/R9 post-mortem): active-CU VALUBusy ~90% -> issue-bound;
// splitting layers across waves cuts per-wave instrs ~2x (64 weights/thr)
// and lets the two recurrence chains overlap in separate waves.
// 1 barrier/step; quad-split activations; h1 chunk-flushed every 64 steps.
// =====================================================================
__global__ __launch_bounds__(768, 1) __attribute__((amdgpu_waves_per_eu(3, 3)))
void lstm_kernel(const float* __restrict__ x,
                 const float* __restrict__ Wih0, const float* __restrict__ Whh0,
                 const float* __restrict__ bih0, const float* __restrict__ bhh0,
                 const float* __restrict__ Wih1, const float* __restrict__ Whh1,
                 const float* __restrict__ bih1, const float* __restrict__ bhh1,
                 float* __restrict__ lstm_out) {
    __shared__ __align__(16) float h0s[2][HH];
    __shared__ __align__(16) float h1s[2][HH];
    __shared__ __align__(16) float xall[TT * DD];    // 32 KB
    __shared__ __align__(16) float hbuf[64 * HH];    // 16 KB output chunk

    const int tid = threadIdx.x;
    const int b   = blockIdx.x;
    const bool isA = (tid < 256);
    const int btid = isA ? tid : (tid - 256);

    // A: u=tid>>2, p=tid&3.  B: u=btid>>3, p=btid&7.
    const int u = isA ? (tid >> 2) : (btid >> 3);
    const int p = isA ? (tid & 3)  : (btid & 7);
    const int q = btid & 3;        // quad lane (gate index) for both groups

    // ---- weights into registers: 16 float4 = 64 floats/thread ----
    float4 wr[4][4];
    float  wx[4], bg[4];
#pragma unroll
    for (int g = 0; g < 4; ++g) {
        const int row = g * 64 + u;
        const float* src;
        int col;
        if (isA) { src = Whh0; col = 16 * p; }
        else if (p < 4) { src = Wih1; col = 16 * p; }
        else { src = Whh1; col = 16 * (p - 4); }
#pragma unroll
        for (int c = 0; c < 4; ++c)
            wr[g][c] = *(const float4*)(src + row * 64 + col + 4 * c);
        wx[g] = (isA && p < 4) ? Wih0[row * 4 + p] : 0.f;
        bg[g] = isA ? (bih0[row] + bhh0[row]) : (bih1[row] + bhh1[row]);
    }
#pragma unroll
    for (int g = 0; g < 4; ++g) {
#pragma unroll
        for (int c = 0; c < 4; ++c) PIN4(wr[g][c]);
        asm volatile("" : "+v"(wx[g]), "+v"(bg[g]));
    }

    // ---- stage all x for this batch ----
    const float* xrow = x + (size_t)b * TT * DD;
    for (int i = tid; i < TT; i += 768)
        *(float4*)(xall + i * 4) = *(const float4*)(xrow + i * 4);
    if (tid < HH) h1s[1][tid] = 0.f;
    float cc = 0.f;            // c0 for A, c1 for B
    __syncthreads();

    // ---- t=0 layer 0 (h0_prev = 0), group A only ----
    if (isA) {
        const float xa = xall[p];
        float gv[4];
#pragma unroll
        for (int g = 0; g < 4; ++g) gv[g] = red4(wx[g] * xa) + bg[g];
        float h0v;
        act_update(gv[0], gv[1], gv[2], gv[3], q, cc, h0v);
        if (p == 0) h0s[0][u] = h0v;
    }

    float* orow = lstm_out + (size_t)b * TT * HH;

    for (int t = 0; t < TT; ++t) {
        __syncthreads();                        // the one barrier per step
        const float* h0c = h0s[t & 1];          // h0(t)
        const float* h1p = h1s[(t + 1) & 1];    // h1(t-1)

        // operand slice for this thread
        const float* hsrc = isA ? h0c : ((p < 4) ? h0c : h1p);
        const int off = (p & 3) * 16;
        float4 hv0 = *(const float4*)(hsrc + off);
        float4 hv1 = *(const float4*)(hsrc + off + 4);
        float4 hv2 = *(const float4*)(hsrc + off + 8);
        float4 hv3 = *(const float4*)(hsrc + off + 12);

        // A computes layer-0 for t+1; B computes layer-1 for t.
        const float xa = isA ? xall[(t + 1 < TT ? t + 1 : t) * 4 + p] : 0.f;
        float gv[4];
#pragma unroll
        for (int g = 0; g < 4; ++g) {
            const float sA = dot4(wr[g][0], hv0) + dot4(wr[g][1], hv1);
            const float sB = dot4(wr[g][2], hv2) + dot4(wr[g][3], hv3);
            gv[g] = wx[g] * xa + sA + sB;
        }
        if (isA) {
#pragma unroll
            for (int g = 0; g < 4; ++g) gv[g] = red4(gv[g]) + bg[g];
            if (t + 1 < TT) {
                float h0v;
                act_update(gv[0], gv[1], gv[2], gv[3], q, cc, h0v);
                if (p == 0) h0s[(t + 1) & 1][u] = h0v;
            }
        } else {
#pragma unroll
            for (int g = 0; g < 4; ++g) gv[g] = red8(gv[g]) + bg[g];
            float h1v;
            act_update(gv[0], gv[1], gv[2], gv[3], q, cc, h1v);
            if (p == 0) h1s[t & 1][u] = h1v;
            if (p == 1) hbuf[(t & 63) * HH + u] = h1v;
        }

        if ((t & 63) == 63) {                   // chunk flush
            __syncthreads();
            float4*       dst = (float4*)(orow + (size_t)(t - 63) * HH);
            const float4* src = (const float4*)hbuf;
            for (int i = tid; i < 1024; i += 768) dst[i] = src[i];
        }
    }
}

// =====================================================================
// Kernel 2: fused q/k/v + windowed attention + MLP head. (unchanged R3)
// Weights read directly from global (L1/L2 broadcast across WGs); LDS
// holds only data tiles (78 KB) -> 2 WGs/CU.
// =====================================================================
#define ATTN_LDS_FLOATS 19560

__global__ __launch_bounds__(256, 2)
void attn_kernel(const float* __restrict__ lstm,
                 const float* __restrict__ Wq, const float* __restrict__ bq,
                 const float* __restrict__ Wk, const float* __restrict__ bk,
                 const float* __restrict__ Wv, const float* __restrict__ bv,
                 const float* __restrict__ Wc, const float* __restrict__ bc,
                 const float* __restrict__ Wo1, const float* __restrict__ bo1,
                 const float* __restrict__ Wo2, const float* __restrict__ bo2,
                 float* __restrict__ out) {
    extern __shared__ __align__(16) float lds[];
    float* bias = lds;            // [256]
    float* ho   = lds + 256;      // [74][64]
    float* kb   = lds + 4992;     // [74][36]
    float* qb   = lds + 7656;     // [64][36]
    float* vb   = lds + 9960;     // [74][64]
    float* swr  = lds + 14696;    // [64][12]
    float* ctxs = lds + 15464;    // [64][64]
    float* cmbs = lds + 4992;     // [64][64] alias (kb+qb dead after scores)
    float* o1s  = lds + 9960;     // [64][33] alias (vb dead after context)

    const int tid  = threadIdx.x;
    const int b    = blockIdx.x >> 5;
    const int tile = blockIdx.x & 31;
    const int t0   = tile * TILE;

    if (tid < 32) {
        bias[tid]       = bq[tid];
        bias[32 + tid]  = bk[tid];
        bias[192 + tid] = bo1[tid];
        bias[224 + tid] = Wo2[tid];
    }
    if (tid >= 64 && tid < 128) {
        const int j = tid - 64;
        bias[64 + j]  = bv[j];
        bias[128 + j] = bc[j];
    }
    for (int i = tid; i < RWS * 16; i += 256) {
        const int row = i >> 4, c = i & 15;
        const int t = t0 - WIN + row;
        float4 v = make_float4(0.f, 0.f, 0.f, 0.f);
        if (t >= 0) v = *(const float4*)(lstm + ((size_t)b * TT + t) * HH + 4 * c);
        *(float4*)(ho + row * 64 + 4 * c) = v;
    }
    __syncthreads();

    // ---- phase 1a: v projection ----
    {
        const int h = tid & 63, rq = tid >> 6;
        const int r0 = rq * 19;
        int ri[19];
        float acc[19];
#pragma unroll
        for (int rr = 0; rr < 19; ++rr) { ri[rr] = min(r0 + rr, RWS - 1); acc[rr] = bias[64 + h]; }
#pragma unroll
        for (int k4 = 0; k4 < 16; ++k4) {
            const float4 w = *(const float4*)(Wv + h * 64 + 4 * k4);
#pragma unroll
            for (int rr = 0; rr < 19; ++rr)
                acc[rr] += dot4(w, *(const float4*)(ho + ri[rr] * 64 + 4 * k4));
        }
#pragma unroll
        for (int rr = 0; rr < 19; ++rr) vb[ri[rr] * 64 + h] = acc[rr];
    }
    // ---- phase 1b: k projection ----
    {
        const int a = tid & 31, rq = tid >> 5;
        const int r0 = rq * 10;
        int ri[10];
        float acc[10];
#pragma unroll
        for (int rr = 0; rr < 10; ++rr) { ri[rr] = min(r0 + rr, RWS - 1); acc[rr] = bias[32 + a]; }
#pragma unroll
        for (int k4 = 0; k4 < 16; ++k4) {
            const float4 w = *(const float4*)(Wk + a * 64 + 4 * k4);
#pragma unroll
            for (int rr = 0; rr < 10; ++rr)
                acc[rr] += dot4(w, *(const float4*)(ho + ri[rr] * 64 + 4 * k4));
        }
#pragma unroll
        for (int rr = 0; rr < 10; ++rr) kb[ri[rr] * 36 + a] = acc[rr];
    }
    // ---- phase 1c: q projection ----
    {
        const int a = tid & 31, rq = tid >> 5;
        float acc[8];
#pragma unroll
        for (int rr = 0; rr < 8; ++rr) acc[rr] = bias[a];
#pragma unroll
        for (int k4 = 0; k4 < 16; ++k4) {
            const float4 w = *(const float4*)(Wq + a * 64 + 4 * k4);
#pragma unroll
            for (int rr = 0; rr < 8; ++rr)
                acc[rr] += dot4(w, *(const float4*)(ho + (rq * 8 + rr + WIN) * 64 + 4 * k4));
        }
#pragma unroll
        for (int rr = 0; rr < 8; ++rr) qb[(rq * 8 + rr) * 36 + a] = acc[rr];
    }
    __syncthreads();

    // ---- phase 2a: scores ----
    for (int i = tid; i < TILE * WIN; i += 256) {
        const int r = i / WIN, l = i - r * WIN;
        const int t = t0 + r;
        float s = -1e30f;
        if (t - 1 - l >= 0) {
            const int kr = r + WIN - 1 - l;
            float acc = 0.f;
#pragma unroll
            for (int a4 = 0; a4 < 8; ++a4)
                acc += dot4(*(const float4*)(qb + r * 36 + 4 * a4),
                            *(const float4*)(kb + kr * 36 + 4 * a4));
            s = acc * 0.17677669529663687f;   // 1/sqrt(32)
        }
        swr[r * 12 + l] = s;
    }
    __syncthreads();
    // ---- phase 2b: softmax per row ----
    if (tid < TILE) {
        const int r = tid;
        float sc[WIN], m = -1e30f;
#pragma unroll
        for (int l = 0; l < WIN; ++l) { sc[l] = swr[r * 12 + l]; m = fmaxf(m, sc[l]); }
        float sum = 0.f;
#pragma unroll
        for (int l = 0; l < WIN; ++l) { sc[l] = __expf(sc[l] - m); sum += sc[l]; }
        const float inv = __fdividef(1.f, sum);
#pragma unroll
        for (int l = 0; l < WIN; ++l) swr[r * 12 + l] = sc[l] * inv;
    }
    __syncthreads();
    // ---- phase 2c: context ----
    for (int i = tid; i < TILE * HH; i += 256) {
        const int r = i >> 6, h = i & 63;
        float acc = 0.f;
#pragma unroll
        for (int l = 0; l < WIN; ++l)
            acc += swr[r * 12 + l] * vb[(r + WIN - 1 - l) * 64 + h];
        ctxs[r * 64 + h] = acc;
    }
    __syncthreads();

    // ---- phase 3: combined ----
    {
        const int h = tid & 63, rq = tid >> 6;
        float acc[16];
#pragma unroll
        for (int rr = 0; rr < 16; ++rr) acc[rr] = bias[128 + h];
#pragma unroll
        for (int k4 = 0; k4 < 16; ++k4) {
            const float4 w = *(const float4*)(Wc + h * 128 + 4 * k4);
#pragma unroll
            for (int rr = 0; rr < 16; ++rr)
                acc[rr] += dot4(w, *(const float4*)(ho + (rq * 16 + rr + WIN) * 64 + 4 * k4));
        }
#pragma unroll
        for (int k4 = 0; k4 < 16; ++k4) {
            const float4 w = *(const float4*)(Wc + h * 128 + 64 + 4 * k4);
#pragma unroll
            for (int rr = 0; rr < 16; ++rr)
                acc[rr] += dot4(w, *(const float4*)(ctxs + (rq * 16 + rr) * 64 + 4 * k4));
        }
        if (t0 == 0 && rq == 0) acc[0] = ho[WIN * 64 + h];   // t==0 bypass
#pragma unroll
        for (int rr = 0; rr < 16; ++rr) cmbs[(rq * 16 + rr) * 64 + h] = acc[rr];
    }
    __syncthreads();

    // ---- phase 4: o1 ----
    {
        const int m = tid & 31, rq = tid >> 5;
        float acc[8];
#pragma unroll
        for (int rr = 0; rr < 8; ++rr) acc[rr] = bias[192 + m];
#pragma unroll
        for (int k4 = 0; k4 < 16; ++k4) {
            const float4 w = *(const float4*)(Wo1 + m * 64 + 4 * k4);
#pragma unroll
            for (int rr = 0; rr < 8; ++rr)
                acc[rr] += dot4(w, *(const float4*)(cmbs + (rq * 8 + rr) * 64 + 4 * k4));
        }
#pragma unroll
        for (int rr = 0; rr < 8; ++rr)
            o1s[(rq * 8 + rr) * 33 + m] = fmaxf(acc[rr], 0.f);
    }
    __syncthreads();

    // ---- phase 5: out ----
    if (tid < TILE) {
        const int r = tid;
        float s = bo2[0];
#pragma unroll
        for (int m = 0; m < 32; ++m) s += o1s[r * 33 + m] * bias[224 + m];
        out[(size_t)b * TT + t0 + r] = 1.5f * tanhf(s);
    }
}

// =====================================================================
extern "C" void kernel_launch(void* const* d_in, const int* in_sizes, int n_in,
                              void* d_out, int out_size, void* d_ws, size_t ws_size,
                              hipStream_t stream) {
    const float* x    = (const float*)d_in[0];
    const float* Wih0 = (const float*)d_in[1];
    const float* Whh0 = (const float*)d_in[2];
    const float* bih0 = (const float*)d_in[3];
    const float* bhh0 = (const float*)d_in[4];
    const float* Wih1 = (const float*)d_in[5];
    const float* Whh1 = (const float*)d_in[6];
    const float* bih1 = (const float*)d_in[7];
    const float* bhh1 = (const float*)d_in[8];
    const float* Wq   = (const float*)d_in[9];
    const float* bq   = (const float*)d_in[10];
    const float* Wk   = (const float*)d_in[11];
    const float* bk   = (const float*)d_in[12];
    const float* Wv   = (const float*)d_in[13];
    const float* bv   = (const float*)d_in[14];
    const float* Wc   = (const float*)d_in[15];
    const float* bc   = (const float*)d_in[16];
    const float* Wo1  = (const float*)d_in[17];
    const float* bo1  = (const float*)d_in[18];
    const float* Wo2  = (const float*)d_in[19];
    const float* bo2  = (const float*)d_in[20];
    float* out = (float*)d_out;

    float* lstm_out = (float*)d_ws;   // B*T*H floats = 64 MB

    lstm_kernel<<<BB, 768, 0, stream>>>(x, Wih0, Whh0, bih0, bhh0,
                                        Wih1, Whh1, bih1, bhh1, lstm_out);

    const int LDS_BYTES = ATTN_LDS_FLOATS * 4;   // 78240
    hipFuncSetAttribute(reinterpret_cast<const void*>(attn_kernel),
                        hipFuncAttributeMaxDynamicSharedMemorySize, LDS_BYTES);
    attn_kernel<<<BB * (TT / TILE), 256, LDS_BYTES, stream>>>(
        lstm_out, Wq, bq, Wk, bk, Wv, bv, Wc, bc, Wo1, bo1, Wo2, bo2, out);
}